// Round 1
// 217.404 us; speedup vs baseline: 1.0113x; 1.0113x over previous
//
#include <hip/hip_runtime.h>
#include <math.h>

#define TPB 256

typedef float f32x4 __attribute__((ext_vector_type(4)));

__global__ __launch_bounds__(TPB) void geo_kernel(const float* __restrict__ coords,
                                                  float* __restrict__ out, int n) {
    // Coord tile: rows base-2 .. base+256 (259 rows = 777 floats), staged via
    // aligned float4 loads starting at global float index 3*base - 8
    // (3*base is a multiple of 4 since base is a multiple of 256).
    __shared__ float s_crd[780];       // 195 float4
    __shared__ float s_v[258 * 3];     // normalized diffs v[base-2 .. base+255]
    __shared__ float s_ang[TPB * 3];   // 3 KB
    __shared__ float s_frm[TPB * 9];   // 9 KB

    const int  tid  = threadIdx.x;
    const int  base = blockIdx.x * TPB;
    const int  r    = base + tid;
    const long n3   = (long)n * 3;
    const long g0   = (long)base * 3;

    // ---- Phase 1: coalesced coords staging --------------------------------
    {
        const long gs = g0 - 8;                 // 16B-aligned start
        if (tid < 195) {
            long gf = gs + 4 * (long)tid;       // global float index of this float4
            float4 val;
            if (gf >= 0 && gf + 4 <= n3) {
                val = *(const float4*)(coords + gf);
            } else {                            // first/last block edges only
                val.x = (gf + 0 >= 0 && gf + 0 < n3) ? coords[gf + 0] : 0.0f;
                val.y = (gf + 1 >= 0 && gf + 1 < n3) ? coords[gf + 1] : 0.0f;
                val.z = (gf + 2 >= 0 && gf + 2 < n3) ? coords[gf + 2] : 0.0f;
                val.w = (gf + 3 >= 0 && gf + 3 < n3) ? coords[gf + 3] : 0.0f;
            }
            *(float4*)(s_crd + 4 * tid) = val;
        }
    }
    __syncthreads();

    // ---- Phase 2: each normalized diff computed ONCE ----------------------
    // v[j] = normalize(coords[j+1]-coords[j]); slot t holds j = base-2+t.
    // Row (base-2+t) starts at s_crd[2 + 3t].
    for (int t = tid; t < 258; t += TPB) {
        long vi = (long)base - 2 + t;
        if (vi >= 0 && vi <= (long)n - 2) {
            const float* c0 = s_crd + 2 + 3 * t;
            float dx = c0[3] - c0[0];
            float dy = c0[4] - c0[1];
            float dz = c0[5] - c0[2];
            float inv = 1.0f / (sqrtf(dx * dx + dy * dy + dz * dz) + 1e-10f);
            s_v[3 * t + 0] = dx * inv;
            s_v[3 * t + 1] = dy * inv;
            s_v[3 * t + 2] = dz * inv;
        }
    }
    __syncthreads();

    // ---- Phase 3: angle + frame per row -----------------------------------
    if (r < n) {
        int rr = r;
        if (rr < 1) rr = 1;
        if (rr > n - 2) rr = n - 2;

        const int lv = rr - base + 1;           // slot of v[rr-1] = (rr-1)-(base-2)
        const float* pv = s_v + 3 * lv;
        float v1x = pv[0], v1y = pv[1], v1z = pv[2];
        float v2x = pv[3], v2y = pv[4], v2z = pv[5];

        float dotv   = v1x * v2x + v1y * v2y + v1z * v2z;
        float cosang = fminf(1.0f, fmaxf(-1.0f, dotv));
        float ang    = (r == 0 || r == n - 1) ? 0.0f : acosf(cosang);

        // Gram-Schmidt: e2 = normalize(v2 - proj*v1), proj = UNclamped dot.
        float tx = v2x - dotv * v1x, ty = v2y - dotv * v1y, tz = v2z - dotv * v1z;
        float invt = 1.0f / (sqrtf(tx * tx + ty * ty + tz * tz) + 1e-10f);
        float e2x = tx * invt, e2y = ty * invt, e2z = tz * invt;

        // e3 = cross(e1, e2)
        float e3x = v1y * e2z - v1z * e2y;
        float e3y = v1z * e2x - v1x * e2z;
        float e3z = v1x * e2y - v1y * e2x;

        s_ang[tid * 3 + 0] = ang;
        s_ang[tid * 3 + 1] = ang;
        s_ang[tid * 3 + 2] = ang;

        float* f = s_frm + tid * 9;
        f[0] = v1x; f[1] = v1y; f[2] = v1z;
        f[3] = e2x; f[4] = e2y; f[5] = e2z;
        f[6] = e3x; f[7] = e3y; f[8] = e3z;
    }
    __syncthreads();

    float* angles = out;                        // n*3 floats
    float* frames = out + (size_t)n * 3;        // n*9 floats

    int valid = n - base;
    if (valid > TPB) valid = TPB;

    if (valid == TPB) {
        // Fully-coalesced float4 flush, non-temporal (pure streaming output).
        f32x4*       ga = (f32x4*)(angles + (size_t)base * 3);
        const f32x4* sa = (const f32x4*)s_ang;
        if (tid < (TPB * 3) / 4)                         // 192 float4s
            __builtin_nontemporal_store(sa[tid], &ga[tid]);

        f32x4*       gf = (f32x4*)(frames + (size_t)base * 9);
        const f32x4* sf = (const f32x4*)s_frm;
        #pragma unroll
        for (int k = 0; k < (TPB * 9) / 4; k += TPB) {   // 576 float4s
            int idx = k + tid;
            if (idx < (TPB * 9) / 4)
                __builtin_nontemporal_store(sf[idx], &gf[idx]);
        }
    } else {
        // Tail block: scalar stores.
        if (r < n) {
            angles[(size_t)r * 3 + 0] = s_ang[tid * 3 + 0];
            angles[(size_t)r * 3 + 1] = s_ang[tid * 3 + 1];
            angles[(size_t)r * 3 + 2] = s_ang[tid * 3 + 2];
            for (int k = 0; k < 9; ++k)
                frames[(size_t)r * 9 + k] = s_frm[tid * 9 + k];
        }
    }
}

extern "C" void kernel_launch(void* const* d_in, const int* in_sizes, int n_in,
                              void* d_out, int out_size, void* d_ws, size_t ws_size,
                              hipStream_t stream) {
    const float* coords = (const float*)d_in[0];
    float*       out    = (float*)d_out;
    int n = in_sizes[0] / 3;
    int blocks = (n + TPB - 1) / TPB;
    hipLaunchKernelGGL(geo_kernel, dim3(blocks), dim3(TPB), 0, stream, coords, out, n);
}